// Round 4
// baseline (212.007 us; speedup 1.0000x reference)
//
#include <hip/hip_runtime.h>

// CG tensor product: 23 (l1,l2,L) triples, C=512. out = 99*C^2 fp32 (~104 MB).
// dur_us is harness-dominated (415MB poison fill ~65us + ~60 graph nodes); the
// kernel itself is <=63us (never in rocprof top-5). This round: strip all
// remaining in-kernel slack.
//  - y[i][t,n,M] = sum_m cg[M,n,m]*x_l1[i,m] precomputed by a tiny kernel into
//    d_ws (512 x 123 rows x 8 padded = 2MB, L2-resident).
//  - main kernel: block=(i, j-half); y loaded to LDS via 246 coalesced float4
//    loads (replaces divergent scattered-cg fill), xj from global (L1-resident),
//    per-thread acc[M] = sum_n y[n,M]*xj[n], nontemporal direct stores.

#define C2 (512 * 512)
#define YROWS 123          // padded-to-8 y rows per i
#define YSTRIDE (YROWS * 8)

struct Ptrs {
    const float* x[4];
    const float* cg[23];
};

// F(t, l1, l2, L, out_base_in_C2_units, y_row_base)
#define TRIPLE_LIST(F) \
    F(0, 0, 0, 0, 0, 0) \
    F(1, 0, 1, 1, 4, 1) \
    F(2, 0, 2, 2, 22, 4) \
    F(3, 0, 3, 3, 57, 9) \
    F(4, 1, 1, 0, 1, 16) \
    F(5, 1, 1, 1, 7, 19) \
    F(6, 1, 1, 2, 27, 22) \
    F(7, 1, 2, 1, 10, 25) \
    F(8, 1, 2, 2, 32, 30) \
    F(9, 1, 2, 3, 64, 35) \
    F(10, 1, 3, 2, 37, 40) \
    F(11, 1, 3, 3, 71, 47) \
    F(12, 2, 2, 0, 2, 54) \
    F(13, 2, 2, 1, 13, 59) \
    F(14, 2, 2, 2, 42, 64) \
    F(15, 2, 2, 3, 78, 69) \
    F(16, 2, 3, 1, 16, 74) \
    F(17, 2, 3, 2, 47, 81) \
    F(18, 2, 3, 3, 85, 88) \
    F(19, 3, 3, 0, 3, 95) \
    F(20, 3, 3, 1, 19, 102) \
    F(21, 3, 3, 2, 52, 109) \
    F(22, 3, 3, 3, 92, 116)

// xj register index base per l2: rows [x0 | x1(3) | x2(5) | x3(7)]
#define XBASE(L2) ((L2) == 0 ? 0 : ((L2) == 1 ? 1 : ((L2) == 2 ? 4 : 9)))

// ---- kernel 1: y precompute. block = one i, threads 0..122 one row each ----
__global__ __launch_bounds__(128) void y_kernel(Ptrs p, float* __restrict__ yall) {
    const int i = blockIdx.x;
    const int r = threadIdx.x;
    if (r >= YROWS) return;
    float* yrow = yall + (size_t)i * YSTRIDE + r * 8;
#define YC(T, L1, L2, LL, OB, RB)                                              \
    if (r >= (RB) && r < (RB) + (2 * L2 + 1)) {                                \
        const int n = r - (RB);                                                \
        const float* cg = p.cg[T];                                             \
        const float* xi = p.x[L1] + i * (2 * L1 + 1);                          \
        _Pragma("unroll")                                                      \
        for (int M = 0; M < 2 * LL + 1; ++M) {                                 \
            float s = 0.f;                                                     \
            _Pragma("unroll")                                                  \
            for (int m = 0; m < 2 * L1 + 1; ++m)                               \
                s = fmaf(cg[(M * (2 * L2 + 1) + n) * (2 * L1 + 1) + m],        \
                         xi[m], s);                                            \
            yrow[M] = s;                                                       \
        }                                                                      \
    }
    TRIPLE_LIST(YC)
#undef YC
}

// ---- kernel 2: main. block b: i=b>>1, j=((b&1)<<8)+tid; all 23 triples ----
template <bool USE_WS>
__global__ __launch_bounds__(256) void cg_tp_kernel(Ptrs p,
                                                    const float* __restrict__ yall,
                                                    float* __restrict__ out) {
    __shared__ float ysh[YSTRIDE];

    const int tid = threadIdx.x;
    const int b = blockIdx.x;
    const int i = b >> 1;
    const int j = ((b & 1) << 8) + tid;

    if (USE_WS) {
        // coalesced float4 copy of this i's y rows (984 floats = 246 float4)
        if (tid < 246)
            ((float4*)ysh)[tid] = ((const float4*)(yall + (size_t)i * YSTRIDE))[tid];
    } else {
        // fallback: in-block y fill (round-3 style)
        if (tid < YROWS) {
            const int r = tid;
#define YC(T, L1, L2, LL, OB, RB)                                              \
            if (r >= (RB) && r < (RB) + (2 * L2 + 1)) {                        \
                const int n = r - (RB);                                        \
                const float* cg = p.cg[T];                                     \
                const float* xi = p.x[L1] + i * (2 * L1 + 1);                  \
                _Pragma("unroll")                                              \
                for (int M = 0; M < 2 * LL + 1; ++M) {                         \
                    float s = 0.f;                                             \
                    _Pragma("unroll")                                          \
                    for (int m = 0; m < 2 * L1 + 1; ++m)                       \
                        s = fmaf(cg[(M * (2 * L2 + 1) + n) * (2 * L1 + 1) + m],\
                                 xi[m], s);                                    \
                    ysh[r * 8 + M] = s;                                        \
                }                                                              \
            }
            TRIPLE_LIST(YC)
#undef YC
        }
    }

    // xj rows straight from global (few KB total -> L1-resident)
    float xj[16];
    {
        xj[0] = p.x[0][j];
        const float* x1 = p.x[1] + j * 3;
        #pragma unroll
        for (int m = 0; m < 3; ++m) xj[1 + m] = x1[m];
        const float* x2 = p.x[2] + j * 5;
        #pragma unroll
        for (int m = 0; m < 5; ++m) xj[4 + m] = x2[m];
        const float* x3 = p.x[3] + j * 7;
        #pragma unroll
        for (int m = 0; m < 7; ++m) xj[9 + m] = x3[m];
    }

    __syncthreads();

    const int pair = i * 512 + j;

#define TC(T, L1, L2, LL, OB, RB)                                              \
    {                                                                          \
        constexpr int NW = 2 * LL + 1;                                         \
        float acc[NW] = {};                                                    \
        const float* y = ysh + (RB) * 8;                                       \
        _Pragma("unroll")                                                      \
        for (int n = 0; n < 2 * L2 + 1; ++n) {                                 \
            const float xv = xj[XBASE(L2) + n];                                \
            _Pragma("unroll")                                                  \
            for (int M = 0; M < NW; ++M)                                       \
                acc[M] = fmaf(y[n * 8 + M], xv, acc[M]);                       \
        }                                                                      \
        float* o = out + (size_t)(OB) * C2 + (size_t)pair * NW;                \
        _Pragma("unroll")                                                      \
        for (int M = 0; M < NW; ++M) __builtin_nontemporal_store(acc[M], o + M); \
    }
    TRIPLE_LIST(TC)
#undef TC
}

extern "C" void kernel_launch(void* const* d_in, const int* in_sizes, int n_in,
                              void* d_out, int out_size, void* d_ws, size_t ws_size,
                              hipStream_t stream) {
    Ptrs p;
    for (int l = 0; l < 4; ++l) p.x[l] = (const float*)d_in[l];
    for (int t = 0; t < 23; ++t) p.cg[t] = (const float*)d_in[4 + t];

    const size_t y_bytes = (size_t)512 * YSTRIDE * sizeof(float);
    if (ws_size >= y_bytes) {
        float* yall = (float*)d_ws;
        y_kernel<<<dim3(512), dim3(128), 0, stream>>>(p, yall);
        cg_tp_kernel<true><<<dim3(1024), dim3(256), 0, stream>>>(p, yall, (float*)d_out);
    } else {
        cg_tp_kernel<false><<<dim3(1024), dim3(256), 0, stream>>>(p, nullptr, (float*)d_out);
    }
}